// Round 2
// baseline (33142.554 us; speedup 1.0000x reference)
//
#include <hip/hip_runtime.h>
#include <hip/hip_bf16.h>

typedef __attribute__((ext_vector_type(8))) short bf16x8;
typedef __attribute__((ext_vector_type(4))) float f32x4;
typedef __attribute__((ext_vector_type(4))) float fvec4;
typedef __attribute__((ext_vector_type(4))) unsigned short u16x4;

#define DEVI __device__ __forceinline__

constexpr int BB = 256, TT = 1024, FF = 128, HH = 512, OO = 64;
constexpr int KK = 256;    // fused input width [x_imp | m]
constexpr int NN = 2048;   // fused gate width  [z | r | htilde | gamma_h]

DEVI unsigned short f2bf(float x) {
  unsigned int u = __float_as_uint(x);
  u += 0x7FFFu + ((u >> 16) & 1u);          // RNE
  return (unsigned short)(u >> 16);
}
DEVI float bf2f(unsigned short s) {
  return __uint_as_float(((unsigned int)s) << 16);
}

// ---------------------------------------------------------------------------
// K0: pack weights.
//   BwT [2048][256] bf16 : row n = column n of fused K x N weight.
//     n<512: z=[W_z;-V_z]  n<1024: r=[W_r;-V_r]  n<1536: h~=[W;-V]
//     n>=1536: gamma=[0;W_gamma_h]
//   bias[2048] f32 : b_* + colsum(V_*)  (gamma rows: b_gamma_h)
//   Uzr [64 tiles][16 kt][64 lane][8] bf16 (tiles 0..31 U_z, 32..63 U_r)
//   Upk [32 tiles][16 kt][64 lane][8] bf16 (U)
//   frag value (tile,kt,l,j) = U[kt*32 + (l>>4)*8 + j][tile*16 + (l&15)]
// ---------------------------------------------------------------------------
__global__ __launch_bounds__(256) void prep_kernel(
    const float* __restrict__ W_z, const float* __restrict__ V_z, const float* __restrict__ b_z,
    const float* __restrict__ W_r, const float* __restrict__ V_r, const float* __restrict__ b_r,
    const float* __restrict__ Wh,  const float* __restrict__ Vh,  const float* __restrict__ bh,
    const float* __restrict__ Wgh, const float* __restrict__ bgh,
    const float* __restrict__ U_z, const float* __restrict__ U_r, const float* __restrict__ Uh,
    unsigned short* __restrict__ BwT, float* __restrict__ bias,
    unsigned short* __restrict__ Uzr, unsigned short* __restrict__ Upk)
{
  int idx = blockIdx.x * 256 + threadIdx.x;
  if (idx < 524288) {                       // BwT
    int n = idx >> 8, k = idx & 255;
    float v;
    if (n < 512)       { int h = n;        v = (k < 128) ? W_z[k*HH + h] : -V_z[(k-128)*HH + h]; }
    else if (n < 1024) { int h = n - 512;  v = (k < 128) ? W_r[k*HH + h] : -V_r[(k-128)*HH + h]; }
    else if (n < 1536) { int h = n - 1024; v = (k < 128) ? Wh [k*HH + h] : -Vh [(k-128)*HH + h]; }
    else               { int h = n - 1536; v = (k < 128) ? 0.f : Wgh[(k-128)*HH + h]; }
    BwT[n*256 + k] = f2bf(v);
    return;
  }
  idx -= 524288;
  if (idx < 2048) {                         // bias
    int n = idx; float v;
    if (n < 512)       { float s = b_z[n];      for (int f = 0; f < FF; ++f) s += V_z[f*HH + n];        v = s; }
    else if (n < 1024) { int h = n-512;  float s = b_r[h]; for (int f = 0; f < FF; ++f) s += V_r[f*HH + h]; v = s; }
    else if (n < 1536) { int h = n-1024; float s = bh[h];  for (int f = 0; f < FF; ++f) s += Vh[f*HH + h];  v = s; }
    else               { v = bgh[n-1536]; }
    bias[n] = v;
    return;
  }
  idx -= 2048;
  if (idx < 524288) {                       // Uzr pack
    int j = idx & 7, l = (idx >> 3) & 63, kt = (idx >> 9) & 15, tile = idx >> 13;
    int k = kt*32 + (l >> 4)*8 + j;
    int col = ((tile < 32) ? tile : tile - 32)*16 + (l & 15);
    float v = (tile < 32) ? U_z[k*HH + col] : U_r[k*HH + col];
    Uzr[idx] = f2bf(v);
    return;
  }
  idx -= 524288;
  if (idx < 262144) {                       // U pack
    int j = idx & 7, l = (idx >> 3) & 63, kt = (idx >> 9) & 15, tile = idx >> 13;
    int k = kt*32 + (l >> 4)*8 + j;
    int col = tile*16 + (l & 15);
    Upk[idx] = f2bf(Uh[k*HH + col]);
  }
}

// ---------------------------------------------------------------------------
// K1: imputation + fused A chunk [B*TC][256] bf16 = [x_imp | m]
//   8 chunk-rows per block (all same b since TC>=8); dead groups skipped.
// ---------------------------------------------------------------------------
__global__ __launch_bounds__(256) void build_A_kernel(
    const float* __restrict__ x, const float* __restrict__ delta,
    const float* __restrict__ mm, const float* __restrict__ xf,
    const float* __restrict__ Wgx, const float* __restrict__ bgx,
    const int* __restrict__ bs, unsigned short* __restrict__ A,
    int t0, int TC)
{
  int blk = blockIdx.x;
  int row8 = blk * 8;                // chunk-local row group start
  int b0  = row8 / TC;
  int tl0 = row8 % TC;
  if (b0 >= bs[t0 + tl0]) return;    // bs descending: whole group inactive
  int tid = threadIdx.x;
  int rl = row8 + (tid >> 5);        // chunk-local row
  int tc = tl0 + (tid >> 5);
  long gi = ((long)b0*TT + t0 + tc) * 32 + (tid & 31);  // global float4 idx
  int f0 = (tid & 31) * 4;
  fvec4 xv = ((const fvec4*)x)[gi];
  fvec4 dv = ((const fvec4*)delta)[gi];
  fvec4 mv = ((const fvec4*)mm)[gi];
  fvec4 fv = ((const fvec4*)xf)[gi];
  unsigned short ox[4], om[4];
#pragma unroll
  for (int j = 0; j < 4; ++j) {
    float g  = __expf(-fmaxf(dv[j]*Wgx[f0+j] + bgx[f0+j], 0.f));
    float xr = g*fv[j] + (1.f - g)*0.001f;
    float xi = (mv[j] > 0.5f) ? xr : xv[j];
    ox[j] = f2bf(xi); om[j] = f2bf(mv[j]);
  }
  *(u16x4*)(A + (long)rl*KK + f0)       = (u16x4){ox[0], ox[1], ox[2], ox[3]};
  *(u16x4*)(A + (long)rl*KK + 128 + f0) = (u16x4){om[0], om[1], om[2], om[3]};
}

// ---------------------------------------------------------------------------
// K2: chunk GEMM  PRE[m][n] = A[m][:] @ Bw[:,n] + bias[n]  (bf16 MFMA, K=256)
//   128x128 tile, 4 waves (2x2), acc 4x4 of 16x16 frags; no LDS (B hot in L2).
//   gamma cols (n>=1536) get exp(-relu(.)). Dead M-tiles skipped.
// ---------------------------------------------------------------------------
__global__ __launch_bounds__(256) void gemm1_kernel(
    const unsigned short* __restrict__ A, const unsigned short* __restrict__ BwT,
    const float* __restrict__ bias, const int* __restrict__ bs,
    unsigned short* __restrict__ PRE, int t0, int TC)
{
  int blk = blockIdx.x;
  int nt = blk & 15;
  int mt = blk >> 4;
  {
    int m0 = mt * 128;
    int b_ = m0 / TC;
    int bcheck = (TC >= 128) ? bs[t0 + (m0 % TC)] : bs[t0];
    if (b_ >= bcheck) return;
  }
  int tid = threadIdx.x;
  int w = tid >> 6, l = tid & 63;
  int wm = w >> 1, wn = w & 1;
  int lr = l & 15, lg = l >> 4;
  int m_base = mt*128 + wm*64;
  int n_base = nt*128 + wn*64;
  const unsigned short* Aptr = A   + (long)(m_base + lr)*KK + lg*8;
  const unsigned short* Bptr = BwT + (long)(n_base + lr)*KK + lg*8;
  f32x4 acc[4][4];
#pragma unroll
  for (int i = 0; i < 4; ++i)
#pragma unroll
    for (int j = 0; j < 4; ++j) acc[i][j] = (f32x4){0.f, 0.f, 0.f, 0.f};

#pragma unroll
  for (int kt = 0; kt < 8; ++kt) {
    bf16x8 af[4], bfr[4];
#pragma unroll
    for (int i = 0; i < 4; ++i) af[i]  = *(const bf16x8*)(Aptr + (long)i*16*KK + kt*32);
#pragma unroll
    for (int i = 0; i < 4; ++i) bfr[i] = *(const bf16x8*)(Bptr + (long)i*16*KK + kt*32);
#pragma unroll
    for (int ms = 0; ms < 4; ++ms)
#pragma unroll
      for (int ns = 0; ns < 4; ++ns)
        acc[ms][ns] = __builtin_amdgcn_mfma_f32_16x16x32_bf16(af[ms], bfr[ns], acc[ms][ns], 0, 0, 0);
  }
#pragma unroll
  for (int ms = 0; ms < 4; ++ms) {
    int gm0 = m_base + ms*16 + lg*4;
#pragma unroll
    for (int ns = 0; ns < 4; ++ns) {
      int gn = n_base + ns*16 + lr;
      float bv = bias[gn];
      bool is_gamma = (gn >= 1536);
#pragma unroll
      for (int q = 0; q < 4; ++q) {
        float v = acc[ms][ns][q] + bv;
        if (is_gamma) v = __expf(-fmaxf(v, 0.f));
        PRE[(long)(gm0 + q)*NN + gn] = f2bf(v);
      }
    }
  }
}

// ---------------------------------------------------------------------------
// K3: sequential scan over one chunk. 16 persistent blocks x 1024 threads;
//   block j owns batch rows [16j,16j+16) (rows are independent). h fp32 in
//   LDS, carried across chunks in h_st. MFMA 16x16x32 bf16, U hot in L2.
// ---------------------------------------------------------------------------
constexpr int RROWS = 16;
constexpr int HPAD = 516;    // h_lds stride (f32)
constexpr int PPAD = 2064;   // pre_lds stride (shorts)
constexpr int RPAD = 520;    // r_lds stride (shorts)

__global__ __launch_bounds__(1024) void scan_kernel(
    const unsigned short* __restrict__ PRE,
    const unsigned short* __restrict__ Uzr,
    const unsigned short* __restrict__ Upk,
    const int* __restrict__ bs,
    float* __restrict__ h_st,
    int t0, int TC)
{
  __shared__ float h_lds[RROWS * HPAD];            // 33.0 KB
  __shared__ unsigned short Apack[16*64*8];        // 16 KB (h_d frags; reused for h_d*r)
  __shared__ unsigned short r_lds[RROWS * RPAD];   // 16.6 KB
  __shared__ unsigned short pre_lds[RROWS * PPAD]; // 66.0 KB

  const int tid = threadIdx.x;
  const int r0 = blockIdx.x * RROWS;
  if (t0 > 0 && bs[t0] <= r0) return;              // inactive whole chunk; h_st valid

  if (t0 == 0) {
    for (int i = tid; i < RROWS*HPAD; i += 1024) h_lds[i] = 0.f;
  } else {
    for (int i = tid; i < RROWS*HH; i += 1024)
      h_lds[(i >> 9)*HPAD + (i & 511)] = h_st[(long)(r0 + (i >> 9))*HH + (i & 511)];
  }

  const int w  = tid >> 6;
  const int l  = tid & 63;
  const int lr = l & 15;
  const int lg = l >> 4;
  // cooperative fragment-build mapping (1024 threads -> 16 kt x 64 lanes)
  const int bk   = tid >> 6;
  const int bl   = tid & 63;
  const int brow = bl & 15;
  const int bk0  = bk*32 + (bl >> 4)*8;

  float zreg[2][4];
  __syncthreads();

  for (int tc = 0; tc < TC; ++tc) {
    const int bsv = bs[t0 + tc];
    if (bsv <= r0) break;                          // descending: done forever
    const int na = min(RROWS, bsv - r0);
    __syncthreads();  // prev-step h writes + pre_lds consumers done

    // stage PRE slab (16 rows x 2048 bf16) for chunk-local time tc
    {
      const unsigned short* src = PRE + ((long)r0*TC + tc)*NN;
#pragma unroll
      for (int c = 0; c < 4; ++c) {
        int idx = tid + c*1024;
        int row = idx >> 8, ch = idx & 255;
        bf16x8 v = *(const bf16x8*)(src + (long)row*TC*NN + ch*8);
        *(bf16x8*)(pre_lds + row*PPAD + ch*8) = v;
      }
    }
    __syncthreads();

    // Apack = h_d = (active ? gamma*h : h), bf16 fragment layout
    {
      const bool act = brow < na;
      const float* hp = h_lds + brow*HPAD + bk0;
      const unsigned short* gp = pre_lds + brow*PPAD + 1536 + bk0;
      unsigned short* ap = Apack + (bk*64 + bl)*8;
#pragma unroll
      for (int j = 0; j < 8; ++j) {
        float hv = hp[j];
        float hd = act ? bf2f(gp[j]) * hv : hv;
        ap[j] = f2bf(hd);
      }
    }
    __syncthreads();

    // phase A: z,r pre-activations; wave w owns cols [32w,32w+32) of each
    {
      f32x4 acc0 = {0.f,0.f,0.f,0.f}, acc1 = acc0, acc2 = acc0, acc3 = acc0;
      const int tz0 = 2*w, tz1 = 2*w + 1, tr0 = 32 + 2*w, tr1 = 33 + 2*w;
#pragma unroll
      for (int kt = 0; kt < 16; ++kt) {
        bf16x8 af = *(const bf16x8*)(Apack + (kt*64 + l)*8);
        bf16x8 b0 = *(const bf16x8*)(Uzr + ((tz0*16 + kt)*64 + l)*8);
        bf16x8 b1 = *(const bf16x8*)(Uzr + ((tz1*16 + kt)*64 + l)*8);
        bf16x8 b2 = *(const bf16x8*)(Uzr + ((tr0*16 + kt)*64 + l)*8);
        bf16x8 b3 = *(const bf16x8*)(Uzr + ((tr1*16 + kt)*64 + l)*8);
        acc0 = __builtin_amdgcn_mfma_f32_16x16x32_bf16(af, b0, acc0, 0, 0, 0);
        acc1 = __builtin_amdgcn_mfma_f32_16x16x32_bf16(af, b1, acc1, 0, 0, 0);
        acc2 = __builtin_amdgcn_mfma_f32_16x16x32_bf16(af, b2, acc2, 0, 0, 0);
        acc3 = __builtin_amdgcn_mfma_f32_16x16x32_bf16(af, b3, acc3, 0, 0, 0);
      }
#pragma unroll
      for (int q = 0; q < 4; ++q) {
        int row = lg*4 + q;
        int c0 = w*32 + lr;
        float p0 = bf2f(pre_lds[row*PPAD + c0]);
        float p1 = bf2f(pre_lds[row*PPAD + c0 + 16]);
        zreg[0][q] = 1.f/(1.f + __expf(-(p0 + acc0[q])));
        zreg[1][q] = 1.f/(1.f + __expf(-(p1 + acc1[q])));
        float pr0 = bf2f(pre_lds[row*PPAD + 512 + c0]);
        float pr1 = bf2f(pre_lds[row*PPAD + 512 + c0 + 16]);
        r_lds[row*RPAD + c0]      = f2bf(1.f/(1.f + __expf(-(pr0 + acc2[q]))));
        r_lds[row*RPAD + c0 + 16] = f2bf(1.f/(1.f + __expf(-(pr1 + acc3[q]))));
      }
    }
    __syncthreads();

    // Apack <- h_d * r (in place: same slot read/write per thread)
    {
      unsigned short* ap = Apack + (bk*64 + bl)*8;
      const unsigned short* rp = r_lds + brow*RPAD + bk0;
#pragma unroll
      for (int j = 0; j < 8; ++j)
        ap[j] = f2bf(bf2f(ap[j]) * bf2f(rp[j]));
    }
    __syncthreads();

    // phase B: h~ and h update; wave w owns cols [32w,32w+32)
    {
      f32x4 acc0 = {0.f,0.f,0.f,0.f}, acc1 = acc0;
      const int ta = 2*w, tb = 2*w + 1;
#pragma unroll
      for (int kt = 0; kt < 16; ++kt) {
        bf16x8 af = *(const bf16x8*)(Apack + (kt*64 + l)*8);
        bf16x8 b0 = *(const bf16x8*)(Upk + ((ta*16 + kt)*64 + l)*8);
        bf16x8 b1 = *(const bf16x8*)(Upk + ((tb*16 + kt)*64 + l)*8);
        acc0 = __builtin_amdgcn_mfma_f32_16x16x32_bf16(af, b0, acc0, 0, 0, 0);
        acc1 = __builtin_amdgcn_mfma_f32_16x16x32_bf16(af, b1, acc1, 0, 0, 0);
      }
#pragma unroll
      for (int q = 0; q < 4; ++q) {
        int row = lg*4 + q;
        if (row < na) {
          int c0 = w*32 + lr;
#pragma unroll
          for (int i = 0; i < 2; ++i) {
            int col = c0 + i*16;
            float a  = (i == 0) ? acc0[q] : acc1[q];
            float ph = bf2f(pre_lds[row*PPAD + 1024 + col]);
            float e  = __expf(2.f*(ph + a));
            float th = 1.f - 2.f/(e + 1.f);               // tanh, overflow-safe
            float g  = bf2f(pre_lds[row*PPAD + 1536 + col]);
            float hd = g * h_lds[row*HPAD + col];
            h_lds[row*HPAD + col] = hd + zreg[i][q]*(th - hd);
          }
        }
      }
    }
  }
  __syncthreads();
  for (int i = tid; i < RROWS*HH; i += 1024) {
    int row = i >> 9, col = i & 511;
    h_st[(long)(r0 + row)*HH + col] = h_lds[row*HPAD + col];
  }
}

// ---------------------------------------------------------------------------
// K4: head: eval BatchNorm + decoder GEMV + log_softmax.
//   d_out = [output (256x64) | h_bn (256x512)] fp32
// ---------------------------------------------------------------------------
__global__ __launch_bounds__(64) void head_kernel(
    const float* __restrict__ h_state, const float* __restrict__ decW,
    const float* __restrict__ decb, const float* __restrict__ bnw,
    const float* __restrict__ bnb, float* __restrict__ out)
{
  int b = blockIdx.x, o = threadIdx.x;
  __shared__ float hbn[HH];
  const float s = rsqrtf(1.f + 1e-5f);
  for (int j = o; j < HH; j += 64)
    hbn[j] = h_state[(long)b*HH + j] * (bnw[j] * s) + bnb[j];
  __syncthreads();
  float acc = decb[o];
  for (int j = 0; j < HH; ++j) acc += hbn[j] * decW[j*OO + o];
  float mx = acc;
#pragma unroll
  for (int off = 32; off > 0; off >>= 1) mx = fmaxf(mx, __shfl_xor(mx, off));
  float ex = __expf(acc - mx);
  float sum = ex;
#pragma unroll
  for (int off = 32; off > 0; off >>= 1) sum += __shfl_xor(sum, off);
  out[(long)b*OO + o] = acc - mx - __logf(sum);
  for (int j = o; j < HH; j += 64)
    out[(long)BB*OO + (long)b*HH + j] = hbn[j];
}

// ---------------------------------------------------------------------------
extern "C" void kernel_launch(void* const* d_in, const int* in_sizes, int n_in,
                              void* d_out, int out_size, void* d_ws, size_t ws_size,
                              hipStream_t stream) {
  const float* x     = (const float*)d_in[0];
  const float* delta = (const float*)d_in[1];
  const float* mm    = (const float*)d_in[2];
  const float* xf    = (const float*)d_in[3];
  const int*   bs    = (const int*)  d_in[4];
  const float* W_r   = (const float*)d_in[5];
  const float* U_r   = (const float*)d_in[6];
  const float* V_r   = (const float*)d_in[7];
  const float* b_r   = (const float*)d_in[8];
  const float* W_z   = (const float*)d_in[9];
  const float* U_z   = (const float*)d_in[10];
  const float* V_z   = (const float*)d_in[11];
  const float* b_z   = (const float*)d_in[12];
  const float* W     = (const float*)d_in[13];
  const float* U     = (const float*)d_in[14];
  const float* V     = (const float*)d_in[15];
  const float* b     = (const float*)d_in[16];
  const float* Wgx   = (const float*)d_in[17];
  const float* bgx   = (const float*)d_in[18];
  const float* Wgh   = (const float*)d_in[19];
  const float* bgh   = (const float*)d_in[20];
  const float* decW  = (const float*)d_in[21];
  const float* decb  = (const float*)d_in[22];
  const float* bnw   = (const float*)d_in[23];
  const float* bnb   = (const float*)d_in[24];

  auto rnd = [](size_t v) { return (v + 255) & ~(size_t)255; };
  const size_t fixed_bytes = rnd((size_t)2048*256*2) + rnd(2048*4)
                           + rnd((size_t)64*16*64*8*2) + rnd((size_t)32*16*64*8*2)
                           + rnd((size_t)BB*HH*4);
  int TC = 0;
  const int cands[5] = {128, 64, 32, 16, 8};
  for (int i = 0; i < 5; ++i) {
    size_t need = fixed_bytes + rnd((size_t)BB*cands[i]*KK*2) + rnd((size_t)BB*cands[i]*NN*2);
    if (need <= ws_size) { TC = cands[i]; break; }
  }
  if (TC == 0) return;  // ws too small for even the minimal config

  char* p = (char*)d_ws;
  auto alloc = [&](size_t bytes) { char* r = p; p += (bytes + 255) & ~(size_t)255; return r; };
  unsigned short* A_chunk = (unsigned short*)alloc((size_t)BB * TC * KK * 2);
  unsigned short* PREc    = (unsigned short*)alloc((size_t)BB * TC * NN * 2);
  unsigned short* BwT     = (unsigned short*)alloc((size_t)2048 * 256 * 2);
  float*          bias    = (float*)alloc(2048 * 4);
  unsigned short* Uzr     = (unsigned short*)alloc((size_t)64*16*64*8 * 2);
  unsigned short* Upk     = (unsigned short*)alloc((size_t)32*16*64*8 * 2);
  float*          h_st    = (float*)alloc((size_t)BB * HH * 4);

  prep_kernel<<<5128, 256, 0, stream>>>(W_z, V_z, b_z, W_r, V_r, b_r, W, V, b,
                                        Wgh, bgh, U_z, U_r, U, BwT, bias, Uzr, Upk);
  const int nch = TT / TC;
  for (int c = 0; c < nch; ++c) {
    int t0 = c * TC;
    build_A_kernel<<<BB*TC/8, 256, 0, stream>>>(x, delta, mm, xf, Wgx, bgx, bs,
                                                A_chunk, t0, TC);
    gemm1_kernel<<<(BB*TC/128)*16, 256, 0, stream>>>(A_chunk, BwT, bias, bs,
                                                     PREc, t0, TC);
    scan_kernel<<<16, 1024, 0, stream>>>(PREc, Uzr, Upk, bs, h_st, t0, TC);
  }
  head_kernel<<<256, 64, 0, stream>>>(h_st, decW, decb, bnw, bnb, (float*)d_out);
}